// Round 1
// 438.666 us; speedup vs baseline: 1.9810x; 1.9810x over previous
//
#include <hip/hip_runtime.h>
#include <hip/hip_bf16.h>

typedef __bf16 bf16_t;
typedef __bf16 bf16x8 __attribute__((ext_vector_type(8)));
typedef float f32x4 __attribute__((ext_vector_type(4)));

#define LDA 264   // k1 X rows (256 + 8)
#define LDX 520   // k2 sX rows [hi 256 | lo 256] + 8
#define LDT 136   // sTh/sTl/sY rows (128 + 8)
#define LDF 264   // sF rows (256 + 8)
#define LDP 136   // staged phi/ww rows (128 + 8)
#define LDG 264   // staged g rows (256 + 8)

__device__ __forceinline__ float ldin(const void* p, long i, int isbf) {
  if (isbf) {
    unsigned short u = ((const unsigned short*)p)[i];
    unsigned int w = ((unsigned int)u) << 16;
    float f; __builtin_memcpy(&f, &w, 4); return f;
  }
  return ((const float*)p)[i];
}

__device__ __forceinline__ bf16_t f2b(float f) {
  unsigned int u; __builtin_memcpy(&u, &f, 4);
  u += 0x7FFFu + ((u >> 16) & 1u);
  unsigned short h = (unsigned short)(u >> 16);
  bf16_t r; __builtin_memcpy(&r, &h, 2); return r;
}

__device__ __forceinline__ float b2f(bf16_t b) {
  unsigned short h; __builtin_memcpy(&h, &b, 2);
  unsigned int u = ((unsigned int)h) << 16;
  float f; __builtin_memcpy(&f, &u, 4); return f;
}

__device__ __forceinline__ float bb2f(unsigned short h) {
  unsigned int u = ((unsigned int)h) << 16;
  float f; __builtin_memcpy(&f, &u, 4); return f;
}

__device__ __forceinline__ unsigned short bbits(bf16_t b) {
  unsigned short h; __builtin_memcpy(&h, &b, 2); return h;
}

// load 4 consecutive input values (fp32 or bf16), vectorized
__device__ __forceinline__ void ld4(const void* p, long i, int isbf, float* v) {
  if (isbf) {
    ushort4 u = *(const ushort4*)((const unsigned short*)p + i);
    v[0] = bb2f(u.x); v[1] = bb2f(u.y); v[2] = bb2f(u.z); v[3] = bb2f(u.w);
  } else {
    float4 f = *(const float4*)((const float*)p + i);
    v[0] = f.x; v[1] = f.y; v[2] = f.z; v[3] = f.w;
  }
}

__device__ __forceinline__ f32x4 mfma(bf16x8 a, bf16x8 b, f32x4 c) {
  return __builtin_amdgcn_mfma_f32_16x16x32_bf16(a, b, c, 0, 0, 0);
}

// ---- dtype detector ----
__global__ void kdetect(const unsigned int* x, int* flag) {
  __shared__ int cnt;
  if (threadIdx.x == 0) cnt = 0;
  __syncthreads();
  int local = 0;
  for (int k = 0; k < 4; ++k) {
    unsigned int u = x[threadIdx.x * 4 + k];
    unsigned int e = (u >> 7) & 0xFFu;
    if (e >= 116u && e <= 133u) local++;
  }
  atomicAdd(&cnt, local);
  __syncthreads();
  if (threadIdx.x == 0) *flag = (cnt > 512) ? 1 : 0;
}

// ---- K0: weight conversion + BN folding ----
__global__ void k0(const void* thw_f, const void* phw, const void* gw, const void* ww_f,
                   const void* wb, const void* gma, const void* bta, const void* mean,
                   const void* var, bf16_t* thwb, bf16_t* phwb, bf16_t* gwb, bf16_t* wwb,
                   float* scw, float* shw, const int* flag) {
  int isbf = *flag;
  int i = blockIdx.x * 256 + threadIdx.x;   // 128 blocks -> 32768 threads
  thwb[i] = f2b(ldin(thw_f, i, isbf));
  phwb[i] = f2b(ldin(phw, i, isbf));
  gwb[i]  = f2b(ldin(gw, i, isbf));
  wwb[i]  = f2b(ldin(ww_f, i, isbf));
  if (i < 256) {
    float s = ldin(gma, i, isbf) * rsqrtf(ldin(var, i, isbf) + 1e-5f);
    scw[i] = s;
    shw[i] = (ldin(wb, i, isbf) - ldin(mean, i, isbf)) * s + ldin(bta, i, isbf);
  }
}

// ---- K1: phi + g convs (shared A), register maxpool (theta removed) ----
__global__ __launch_bounds__(256) void k1(const void* xin, const bf16_t* phwb,
    const bf16_t* gwb, const void* phb, const void* gbb,
    bf16_t* phiH, bf16_t* phiL, bf16_t* gT, const int* flag) {
  int isbf = *flag;
  int wg = blockIdx.x;          // 128 tiles * 16 j
  int tile = wg >> 4, j = wg & 15;
  int bi = tile >> 4, t16 = tile & 15, ty = t16 >> 2, tx = t16 & 3;
  long xb = (long)bi * 256 * 16384 + (long)(ty * 32 + 2 * j) * 128 + tx * 32;

  __shared__ __align__(16) bf16_t sX[64 * LDA];   // X^T [64 px][256 c], hi only

  int tid = threadIdx.x, lane = tid & 63, wv = tid >> 6;
  int qd = lane >> 4, ln = lane & 15, kq = qd * 8;

  // vectorized x load: thread handles 4 consecutive w-pixels (fixed c) per iter
  {
    int mq = tid & 15, c0 = tid >> 4;
    int ma = (mq >> 3) * 128 + (mq & 7) * 4;
    #pragma unroll
    for (int it = 0; it < 16; ++it) {
      int c = it * 16 + c0;
      float v[4];
      ld4(xin, xb + (long)c * 16384 + ma, isbf, v);
      #pragma unroll
      for (int r = 0; r < 4; ++r) sX[(mq * 4 + r) * LDA + c] = f2b(v[r]);
    }
  }
  __syncthreads();

  f32x4 accP[4][2], accG[4][2];
  for (int mb = 0; mb < 4; ++mb) {
    const bf16_t* A = sX + (mb * 16 + ln) * LDA;
    bf16x8 af[8];
    #pragma unroll
    for (int c = 0; c < 8; ++c) af[c] = *(const bf16x8*)(A + c * 32 + kq);
    #pragma unroll
    for (int h = 0; h < 2; ++h) {
      int nt = wv + h * 4;
      const bf16_t* Bp = phwb + (nt * 16 + ln) * 256;
      const bf16_t* Bg = gwb + (nt * 16 + ln) * 256;
      f32x4 ap = {0.f,0.f,0.f,0.f}, ag = {0.f,0.f,0.f,0.f};
      #pragma unroll
      for (int c = 0; c < 8; ++c) {
        int ko = c * 32 + kq;
        ap = mfma(af[c], *(const bf16x8*)(Bp + ko), ap);
        ag = mfma(af[c], *(const bf16x8*)(Bg + ko), ag);
      }
      accP[mb][h] = ap; accG[mb][h] = ag;
    }
  }

  // register 2x2 maxpool: cols (r,r+1), rows via mb partner mb+2
  for (int mb2 = 0; mb2 < 2; ++mb2)
    #pragma unroll
    for (int h = 0; h < 2; ++h) {
      int o = (wv + h * 4) * 16 + ln;
      float pb = ldin(phb, o, isbf), gb2 = ldin(gbb, o, isbf);
      #pragma unroll
      for (int r = 0; r < 4; r += 2) {
        float v = fmaxf(fmaxf(accP[mb2][h][r], accP[mb2][h][r + 1]),
                        fmaxf(accP[mb2 + 2][h][r], accP[mb2 + 2][h][r + 1]));
        float u = fmaxf(fmaxf(accG[mb2][h][r], accG[mb2][h][r + 1]),
                        fmaxf(accG[mb2 + 2][h][r], accG[mb2 + 2][h][r + 1]));
        int cp = mb2 * 8 + qd * 2 + (r >> 1);
        int kpos = j * 16 + cp;
        float pv = v + pb;
        bf16_t hi = f2b(pv);
        phiH[(long)tile * 32768 + kpos * 128 + o] = hi;
        phiL[(long)tile * 32768 + kpos * 128 + o] = f2b(pv - b2f(hi));
        gT[(long)tile * 32768 + (long)o * 256 + kpos] = f2b(u + gb2);
      }
    }
}

// ---- K2: in-kernel theta, staged B operands, register softmax, fused epilogue ----
__global__ __launch_bounds__(256, 3) void k2(const void* xin, const bf16_t* thwb,
    const void* thb, const bf16_t* phiH, const bf16_t* phiL, const bf16_t* gT,
    const bf16_t* wwb, const float* sc, const float* sh, void* outv, const int* flag) {
  int isbf = *flag;
  // XCD swizzle: 4096 blocks, all 32 qb-blocks of a tile on one XCD (phi/g L2-local)
  int wg = (blockIdx.x & 7) * 512 + (blockIdx.x >> 3);
  int tile = wg >> 5, qb = wg & 31;
  int bi = tile >> 4, t16 = tile & 15, ty = t16 >> 2, tx = t16 & 3;
  long xbase = (long)bi * 256 * 16384 + (long)(ty * 32 + qb) * 128 + tx * 32;

  __shared__ __align__(16) char smem[51200];
  bf16_t* sX   = (bf16_t*)smem;            // [32][520] hi|lo, theta phase only
  bf16_t* sPh  = (bf16_t*)smem;            // staging R1: phi hi [32][136]
  bf16_t* sPl  = (bf16_t*)(smem + 8704);   //             phi lo [32][136]
  bf16_t* sG   = (bf16_t*)smem;            //             g [32][264]
  bf16_t* sW   = (bf16_t*)smem;            //             ww [64][136]
  bf16_t* sY   = (bf16_t*)(smem + 17408);  // [32][136]
  bf16_t* sTh  = (bf16_t*)(smem + 33280);  // [32][136]
  bf16_t* sTl  = (bf16_t*)(smem + 41984);  // [32][136]
  bf16_t* sF   = (bf16_t*)(smem + 33280);  // [32][264] alias sTh/sTl
  float* sredM = (float*)(smem + 50688);   // 64 f
  float* sredS = (float*)(smem + 50944);   // 64 f

  int tid = threadIdx.x, lane = tid & 63, wv = tid >> 6;
  int qd = lane >> 4, ln = lane & 15, kq = qd * 8;
  int ms = wv >> 1, half = wv & 1;
  int m0 = ms * 16 + qd * 4;

  // ---- x slab (row qb: 32 px x 256 c) -> sX [hi|lo], vectorized ----
  {
    int wq = tid & 7, c0 = tid >> 3;
    #pragma unroll
    for (int it = 0; it < 8; ++it) {
      int c = it * 32 + c0;
      float v[4];
      ld4(xin, xbase + (long)c * 16384 + wq * 4, isbf, v);
      #pragma unroll
      for (int r = 0; r < 4; ++r) {
        bf16_t hi = f2b(v[r]);
        sX[(wq * 4 + r) * LDX + c] = hi;
        sX[(wq * 4 + r) * LDX + 256 + c] = f2b(v[r] - b2f(hi));
      }
    }
  }
  __syncthreads();

  // ---- theta = Xhi @ thw (same math as old k1), split hi/lo into LDS ----
  {
    bf16x8 Axf[8];
    #pragma unroll
    for (int t = 0; t < 4; ++t) {
      int tms = t >> 1, tns = (t & 1) * 4 + wv;
      if ((t & 1) == 0) {
        const bf16_t* A = sX + (tms * 16 + ln) * LDX;
        #pragma unroll
        for (int c = 0; c < 8; ++c) Axf[c] = *(const bf16x8*)(A + c * 32 + kq);
      }
      const bf16_t* B = thwb + (tns * 16 + ln) * 256;
      f32x4 a = {0.f,0.f,0.f,0.f};
      #pragma unroll
      for (int c = 0; c < 8; ++c) a = mfma(Axf[c], *(const bf16x8*)(B + c * 32 + kq), a);
      float bias = ldin(thb, tns * 16 + ln, isbf);
      #pragma unroll
      for (int r = 0; r < 4; ++r) {
        float v = a[r] + bias;
        bf16_t hi = f2b(v);
        int mrow = tms * 16 + qd * 4 + r;
        sTh[mrow * LDT + tns * 16 + ln] = hi;
        sTl[mrow * LDT + tns * 16 + ln] = f2b(v - b2f(hi));
      }
    }
  }

  const bf16_t* PH = phiH + (long)tile * 32768;
  const bf16_t* PL = phiL + (long)tile * 32768;
  const bf16_t* GG = gT + (long)tile * 32768;

  // prefetch phi chunk 0 (in flight across residual extract + barrier)
  uint4 pf0 = *(const uint4*)(PH + tid * 8);
  uint4 pf1 = *(const uint4*)(PH + 2048 + tid * 8);
  uint4 pf2 = *(const uint4*)(PL + tid * 8);
  uint4 pf3 = *(const uint4*)(PL + 2048 + tid * 8);

  // ---- residual extract from sX (hi+lo ~= fp32 x) before sX is overwritten ----
  f32x4 xres[8];
  #pragma unroll
  for (int c4 = 0; c4 < 4; ++c4) {
    #pragma unroll
    for (int jj = 0; jj < 2; ++jj) {
      int o = c4 * 64 + (half * 2 + jj) * 16 + ln;
      f32x4 xr;
      #pragma unroll
      for (int r = 0; r < 4; ++r)
        xr[r] = b2f(sX[(m0 + r) * LDX + o]) + b2f(sX[(m0 + r) * LDX + 256 + o]);
      xres[c4 * 2 + jj] = xr;
    }
  }
  __syncthreads();   // sX reads done; sTh/sTl visible

  // theta A-frags (registers; sTh/sTl dead after this, sF may alias)
  bf16x8 Ah[4], Al[4];
  {
    const bf16_t* th = sTh + (ms * 16 + ln) * LDT;
    const bf16_t* tl = sTl + (ms * 16 + ln) * LDT;
    #pragma unroll
    for (int c = 0; c < 4; ++c) {
      Ah[c] = *(const bf16x8*)(th + c * 32 + kq);
      Al[c] = *(const bf16x8*)(tl + c * 32 + kq);
    }
  }

  int srow = tid >> 4, scol = (tid & 15) * 8;   // 128-wide staging coords
  int grow = tid >> 5, gcol = (tid & 31) * 8;   // 256-wide staging coords

  // ---- S = theta @ phi^T (3-term split), 8 staged chunks of 32 k-rows ----
  f32x4 S[8];
  #pragma unroll
  for (int c = 0; c < 8; ++c) {
    *(uint4*)(sPh + srow * LDP + scol) = pf0;
    *(uint4*)(sPh + (srow + 16) * LDP + scol) = pf1;
    *(uint4*)(sPl + srow * LDP + scol) = pf2;
    *(uint4*)(sPl + (srow + 16) * LDP + scol) = pf3;
    if (c < 7) {
      pf0 = *(const uint4*)(PH + (c + 1) * 4096 + tid * 8);
      pf1 = *(const uint4*)(PH + (c + 1) * 4096 + 2048 + tid * 8);
      pf2 = *(const uint4*)(PL + (c + 1) * 4096 + tid * 8);
      pf3 = *(const uint4*)(PL + (c + 1) * 4096 + 2048 + tid * 8);
    } else {       // seed g chunk 0 (hides under chunk-7 mfma + softmax)
      pf0 = *(const uint4*)(GG + tid * 8);
      pf1 = *(const uint4*)(GG + 2048 + tid * 8);
      pf2 = *(const uint4*)(GG + 4096 + tid * 8);
      pf3 = *(const uint4*)(GG + 6144 + tid * 8);
    }
    __syncthreads();
    const bf16_t* Bh = sPh + (half * 16 + ln) * LDP;
    const bf16_t* Bl = sPl + (half * 16 + ln) * LDP;
    f32x4 a = {0.f,0.f,0.f,0.f};
    #pragma unroll
    for (int kk = 0; kk < 4; ++kk) {
      int ko = kk * 32 + kq;
      bf16x8 bh = *(const bf16x8*)(Bh + ko);
      bf16x8 bl = *(const bf16x8*)(Bl + ko);
      a = mfma(Ah[kk], bl, a);
      a = mfma(Al[kk], bh, a);
      a = mfma(Ah[kk], bh, a);
    }
    S[c] = a;        // cols n = c*32 + half*16 + ln
    __syncthreads();
  }

  // ---- register softmax: shfl over 16-lane group + 2-way LDS exchange ----
  float Mr[4], Sr[4], inv4[4];
  #pragma unroll
  for (int r = 0; r < 4; ++r) {
    float m = S[0][r];
    #pragma unroll
    for (int t = 1; t < 8; ++t) m = fmaxf(m, S[t][r]);
    #pragma unroll
    for (int d = 1; d < 16; d <<= 1) m = fmaxf(m, __shfl_xor(m, d, 64));
    Mr[r] = m;
  }
  if (ln == 0) {
    #pragma unroll
    for (int r = 0; r < 4; ++r) sredM[(m0 + r) * 2 + half] = Mr[r];
  }
  __syncthreads();
  #pragma unroll
  for (int r = 0; r < 4; ++r) Mr[r] = fmaxf(Mr[r], sredM[(m0 + r) * 2 + (half ^ 1)]);
  #pragma unroll
  for (int r = 0; r < 4; ++r) {
    float s = 0.f;
    #pragma unroll
    for (int t = 0; t < 8; ++t) { float e = __expf(S[t][r] - Mr[r]); S[t][r] = e; s += e; }
    #pragma unroll
    for (int d = 1; d < 16; d <<= 1) s += __shfl_xor(s, d, 64);
    Sr[r] = s;
  }
  if (ln == 0) {
    #pragma unroll
    for (int r = 0; r < 4; ++r) sredS[(m0 + r) * 2 + half] = Sr[r];
  }
  __syncthreads();
  #pragma unroll
  for (int r = 0; r < 4; ++r) inv4[r] = 1.f / (Sr[r] + sredS[(m0 + r) * 2 + (half ^ 1)]);

  // F -> sF (aliases sTh/sTl; theta frags are in regs)
  #pragma unroll
  for (int c = 0; c < 8; ++c) {
    int n = c * 32 + half * 16 + ln;
    #pragma unroll
    for (int r = 0; r < 4; ++r)
      sF[(m0 + r) * LDF + n] = f2b(S[c][r] * inv4[r]);
  }
  __syncthreads();

  // ---- y = F @ g, 4 staged chunks of 32 i-rows ----
  bf16x8 Fa[8];
  {
    const bf16_t* fa = sF + (ms * 16 + ln) * LDF;
    #pragma unroll
    for (int c = 0; c < 8; ++c) Fa[c] = *(const bf16x8*)(fa + c * 32 + kq);
  }
  #pragma unroll
  for (int c = 0; c < 4; ++c) {
    *(uint4*)(sG + grow * LDG + gcol) = pf0;
    *(uint4*)(sG + (grow + 8) * LDG + gcol) = pf1;
    *(uint4*)(sG + (grow + 16) * LDG + gcol) = pf2;
    *(uint4*)(sG + (grow + 24) * LDG + gcol) = pf3;
    if (c < 3) {
      pf0 = *(const uint4*)(GG + (c + 1) * 8192 + tid * 8);
      pf1 = *(const uint4*)(GG + (c + 1) * 8192 + 2048 + tid * 8);
      pf2 = *(const uint4*)(GG + (c + 1) * 8192 + 4096 + tid * 8);
      pf3 = *(const uint4*)(GG + (c + 1) * 8192 + 6144 + tid * 8);
    } else {       // seed ww chunk 0
      pf0 = *(const uint4*)(wwb + tid * 8);
      pf1 = *(const uint4*)(wwb + 2048 + tid * 8);
      pf2 = *(const uint4*)(wwb + 4096 + tid * 8);
      pf3 = *(const uint4*)(wwb + 6144 + tid * 8);
    }
    __syncthreads();
    const bf16_t* Bg = sG + (half * 16 + ln) * LDG;
    f32x4 a = {0.f,0.f,0.f,0.f};
    #pragma unroll
    for (int kk = 0; kk < 8; ++kk)
      a = mfma(Fa[kk], *(const bf16x8*)(Bg + kk * 32 + kq), a);
    #pragma unroll
    for (int r = 0; r < 4; ++r)
      sY[(m0 + r) * LDT + c * 32 + half * 16 + ln] = f2b(a[r]);
    __syncthreads();
  }

  // ---- wy = y @ ww^T, BN, residual, direct store; 4 staged chunks of 64 o-rows ----
  bf16x8 Ya[4];
  {
    const bf16_t* ya = sY + (ms * 16 + ln) * LDT;
    #pragma unroll
    for (int kk = 0; kk < 4; ++kk) Ya[kk] = *(const bf16x8*)(ya + kk * 32 + kq);
  }
  #pragma unroll
  for (int c = 0; c < 4; ++c) {
    *(uint4*)(sW + srow * LDP + scol) = pf0;
    *(uint4*)(sW + (srow + 16) * LDP + scol) = pf1;
    *(uint4*)(sW + (srow + 32) * LDP + scol) = pf2;
    *(uint4*)(sW + (srow + 48) * LDP + scol) = pf3;
    if (c < 3) {
      pf0 = *(const uint4*)(wwb + (c + 1) * 8192 + tid * 8);
      pf1 = *(const uint4*)(wwb + (c + 1) * 8192 + 2048 + tid * 8);
      pf2 = *(const uint4*)(wwb + (c + 1) * 8192 + 4096 + tid * 8);
      pf3 = *(const uint4*)(wwb + (c + 1) * 8192 + 6144 + tid * 8);
    }
    __syncthreads();
    #pragma unroll
    for (int jj = 0; jj < 2; ++jj) {
      int nsL = half * 2 + jj;
      const bf16_t* B = sW + (nsL * 16 + ln) * LDP;
      f32x4 a = {0.f,0.f,0.f,0.f};
      #pragma unroll
      for (int kk = 0; kk < 4; ++kk)
        a = mfma(Ya[kk], *(const bf16x8*)(B + kk * 32 + kq), a);
      int o = c * 64 + nsL * 16 + ln;
      float s = sc[o], hh = sh[o];
      f32x4 xr = xres[c * 2 + jj];
      long oi = (long)tile * 262144 + (long)o * 1024 + qb * 32 + m0;
      if (isbf) {
        unsigned short u[4];
        #pragma unroll
        for (int r = 0; r < 4; ++r) u[r] = bbits(f2b(a[r] * s + hh + xr[r]));
        __builtin_memcpy((unsigned short*)outv + oi, u, 8);
      } else {
        float vv[4];
        #pragma unroll
        for (int r = 0; r < 4; ++r) vv[r] = a[r] * s + hh + xr[r];
        __builtin_memcpy((float*)outv + oi, vv, 16);
      }
    }
    __syncthreads();
  }
}

extern "C" void kernel_launch(void* const* d_in, const int* in_sizes, int n_in,
                              void* d_out, int out_size, void* d_ws, size_t ws_size,
                              hipStream_t stream) {
  (void)in_sizes; (void)n_in; (void)out_size; (void)ws_size;
  const void* x    = d_in[0];
  const void* thwf = d_in[1];
  const void* thb  = d_in[2];
  const void* phw  = d_in[3];
  const void* phb  = d_in[4];
  const void* gwf  = d_in[5];
  const void* gbb  = d_in[6];
  const void* wwf  = d_in[7];
  const void* wb   = d_in[8];
  const void* gma  = d_in[9];
  const void* bta  = d_in[10];
  const void* mn   = d_in[11];
  const void* vr   = d_in[12];

  char* ws = (char*)d_ws;
  bf16_t* thwb = (bf16_t*)(ws);                    // 65536
  bf16_t* phwb = (bf16_t*)(ws + 65536);            // 65536
  bf16_t* gwb  = (bf16_t*)(ws + 131072);           // 65536
  bf16_t* wwb  = (bf16_t*)(ws + 196608);           // 65536
  float*  sc   = (float*)(ws + 262144);            // 1024
  float*  sh   = (float*)(ws + 263168);            // 1024
  int*    flag = (int*)(ws + 264192);              // 256
  bf16_t* phiH = (bf16_t*)(ws + 264448);           // 8388608  [tile][k][i]
  bf16_t* phiL = (bf16_t*)(ws + 264448 + 8388608); // 8388608
  bf16_t* gT   = (bf16_t*)(ws + 264448 + 16777216);// 8388608  [tile][i][k]

  kdetect<<<1, 256, 0, stream>>>((const unsigned int*)x, flag);
  k0<<<128, 256, 0, stream>>>(thwf, phw, gwf, wwf, wb, gma, bta, mn, vr,
                              thwb, phwb, gwb, wwb, sc, sh, flag);
  k1<<<2048, 256, 0, stream>>>(x, phwb, gwb, phb, gbb, phiH, phiL, gT, flag);
  k2<<<4096, 256, 0, stream>>>(x, thwb, thb, phiH, phiL, gT, wwb, sc, sh,
                               d_out, flag);
}